// Round 1
// baseline (300.596 us; speedup 1.0000x reference)
//
#include <hip/hip_runtime.h>

namespace {
constexpr int kBB = 64, kH = 64, kW = 64, kC = 128, kP = 64;
constexpr int kHW = kH * kW;                 // 4096
constexpr long kRows = (long)kBB * kHW;      // 262144
constexpr long kOutElems = kRows * kC;       // 33554432

// ---------------- GEMM: out[row][c] = sum_p s[row][p] * k[p][c] ----------------
// 256 threads/block, 64 rows/block, each thread: 8 rows x 4 c's (float4).
// k (64x128 fp32 = 32 KB) staged in LDS once per block; s tile 64x64 = 16 KB.
__global__ __launch_bounds__(256) void gemm_out(const float* __restrict__ s,
                                                const float* __restrict__ kmat,
                                                float* __restrict__ out) {
  __shared__ float4 k_lds[kP][kC / 4];   // [64][32] = 32 KB
  __shared__ float4 s_lds[64][kP / 4];   // [64][16] = 16 KB
  const int t = threadIdx.x;

  // stage k: 2048 float4 / 256 threads = 8 each, coalesced (L2-resident after 1st block)
  const float4* k4 = reinterpret_cast<const float4*>(kmat);
  float4* k_flat = &k_lds[0][0];
#pragma unroll
  for (int i = 0; i < 8; ++i) k_flat[t + 256 * i] = k4[t + 256 * i];

  // stage s tile: 64 rows x 16 float4 = 1024 float4 / 256 threads = 4 each
  const long rowbase = (long)blockIdx.x * 64;
  const float4* s4 = reinterpret_cast<const float4*>(s + rowbase * kP);
  float4* s_flat = &s_lds[0][0];
#pragma unroll
  for (int i = 0; i < 4; ++i) s_flat[t + 256 * i] = s4[t + 256 * i];

  __syncthreads();

  const int cq = t & 31;   // which float4 of the 128 c's
  const int tg = t >> 5;   // row-group 0..7
  float4 acc[8];
#pragma unroll
  for (int j = 0; j < 8; ++j) acc[j] = make_float4(0.f, 0.f, 0.f, 0.f);

  for (int pc = 0; pc < 16; ++pc) {  // p in chunks of 4
    const float4 k0 = k_lds[4 * pc + 0][cq];
    const float4 k1 = k_lds[4 * pc + 1][cq];
    const float4 k2 = k_lds[4 * pc + 2][cq];
    const float4 k3 = k_lds[4 * pc + 3][cq];
#pragma unroll
    for (int j = 0; j < 8; ++j) {
      const float4 sv = s_lds[tg + 8 * j][pc];  // broadcast across 32 lanes
      acc[j].x += sv.x * k0.x + sv.y * k1.x + sv.z * k2.x + sv.w * k3.x;
      acc[j].y += sv.x * k0.y + sv.y * k1.y + sv.z * k2.y + sv.w * k3.y;
      acc[j].z += sv.x * k0.z + sv.y * k1.z + sv.z * k2.z + sv.w * k3.z;
      acc[j].w += sv.x * k0.w + sv.y * k1.w + sv.z * k2.w + sv.w * k3.w;
    }
  }

  float4* out4 = reinterpret_cast<float4*>(out + rowbase * kC);
#pragma unroll
  for (int j = 0; j < 8; ++j) out4[(tg + 8 * j) * 32 + cq] = acc[j];
}

// ---------------- z reduction: zsum[b][c] = sum_hw z, z2[b] = sum z^2 ----------------
// grid = 64 b * 8 chunks; each block streams 512 rows of 128 floats.
__global__ __launch_bounds__(256) void z_reduce(const float* __restrict__ z,
                                               float* __restrict__ zsum,
                                               float* __restrict__ z2) {
  const int b = blockIdx.x >> 3;
  const int chunk = blockIdx.x & 7;
  const int t = threadIdx.x;
  const int cq = t & 31;
  const int tg = t >> 5;
  const float4* zb = reinterpret_cast<const float4*>(z) + (long)b * kHW * (kC / 4);
  const int rowbase = chunk * 512;

  float sx = 0.f, sy = 0.f, sz = 0.f, sw = 0.f, q = 0.f;
  for (int i = 0; i < 64; ++i) {
    const int r = rowbase + tg + 8 * i;
    const float4 v = zb[(long)r * 32 + cq];
    sx += v.x; sy += v.y; sz += v.z; sw += v.w;
    q += v.x * v.x + v.y * v.y + v.z * v.z + v.w * v.w;
  }

  __shared__ float4 red[8][32];
  __shared__ float qred[4];
  red[tg][cq] = make_float4(sx, sy, sz, sw);
  // wave-64 reduce of q
  for (int off = 32; off > 0; off >>= 1) q += __shfl_down(q, off, 64);
  if ((t & 63) == 0) qred[t >> 6] = q;
  __syncthreads();

  if (tg == 0) {
    float4 tot = red[0][cq];
#pragma unroll
    for (int j = 1; j < 8; ++j) {
      const float4 v = red[j][cq];
      tot.x += v.x; tot.y += v.y; tot.z += v.z; tot.w += v.w;
    }
    atomicAdd(&zsum[b * kC + cq * 4 + 0], tot.x);
    atomicAdd(&zsum[b * kC + cq * 4 + 1], tot.y);
    atomicAdd(&zsum[b * kC + cq * 4 + 2], tot.z);
    atomicAdd(&zsum[b * kC + cq * 4 + 3], tot.w);
  }
  if (t == 0) atomicAdd(&z2[b], qred[0] + qred[1] + qred[2] + qred[3]);
}

// ---------------- distance[b][p] = z2[b] - 2*dot(zsum[b],k[p]) + 4096*||k[p]||^2 ----
__global__ __launch_bounds__(256) void dist_kernel(const float* __restrict__ zsum,
                                                   const float* __restrict__ z2,
                                                   const float* __restrict__ kmat,
                                                   float* __restrict__ dist) {
  const int g = blockIdx.x * 256 + threadIdx.x;  // 0..4095
  const int b = g >> 6;
  const int p = g & 63;
  float dot = 0.f, k2 = 0.f;
  for (int c = 0; c < kC; ++c) {
    const float kv = kmat[p * kC + c];
    dot += zsum[b * kC + c] * kv;
    k2 += kv * kv;
  }
  dist[g] = z2[b] - 2.f * dot + (float)kHW * k2;
}

}  // namespace

extern "C" void kernel_launch(void* const* d_in, const int* in_sizes, int n_in,
                              void* d_out, int out_size, void* d_ws, size_t ws_size,
                              hipStream_t stream) {
  const float* z = (const float*)d_in[0];      // (64,64,64,128)
  const float* s = (const float*)d_in[1];      // (64,64,64,64)
  const float* kmat = (const float*)d_in[2];   // (64,1,1,128) -> (64,128)

  float* out = (float*)d_out;                  // 33554432 floats
  float* dist = out + kOutElems;               // 4096 floats

  float* zsum = (float*)d_ws;                  // 64*128 floats
  float* z2 = zsum + kBB * kC;                 // 64 floats

  // zero the atomic accumulators (ws is poisoned 0xAA each call)
  hipMemsetAsync(d_ws, 0, (size_t)(kBB * kC + kBB) * sizeof(float), stream);

  z_reduce<<<kBB * 8, 256, 0, stream>>>(z, zsum, z2);
  gemm_out<<<(int)(kRows / 64), 256, 0, stream>>>(s, kmat, out);
  dist_kernel<<<16, 256, 0, stream>>>(zsum, z2, kmat, dist);
}

// Round 2
// 288.075 us; speedup vs baseline: 1.0435x; 1.0435x over previous
//
#include <hip/hip_runtime.h>

namespace {
constexpr int kBB = 64, kH = 64, kW = 64, kC = 128, kP = 64;
constexpr int kHW = kH * kW;                 // 4096
constexpr long kRows = (long)kBB * kHW;      // 262144
constexpr long kOutElems = kRows * kC;       // 33554432

// Fused: per 64-row block
//   (a) out[row][c] = sum_p s[row][p] * k[p][c]       (register-tiled vector GEMM)
//   (b) partial zsum[b][c] += sum_rows z[row][c],  z2[b] += sum z^2   (atomics)
__global__ __launch_bounds__(256) void fused_kernel(const float* __restrict__ z,
                                                    const float* __restrict__ s,
                                                    const float* __restrict__ kmat,
                                                    float* __restrict__ out,
                                                    float* __restrict__ zsum,
                                                    float* __restrict__ z2) {
  __shared__ float4 k_lds[kP][kC / 4];   // 32 KB
  __shared__ float4 s_lds[64][kP / 4];   // 16 KB
  __shared__ float4 red[8][32];          // 4 KB (z column partials)
  __shared__ float qred[4];

  const int t = threadIdx.x;
  const int cq = t & 31;   // float4-column 0..31
  const int tg = t >> 5;   // row-group 0..7
  const long rowbase = (long)blockIdx.x * 64;
  const int b = (int)(rowbase >> 12);    // 4096 rows per batch image

  // ---- stage k (32 KB, L2-resident after first touch) ----
  const float4* k4 = reinterpret_cast<const float4*>(kmat);
  float4* k_flat = &k_lds[0][0];
#pragma unroll
  for (int i = 0; i < 8; ++i) k_flat[t + 256 * i] = k4[t + 256 * i];

  // ---- stage s tile (contiguous 16 KB) ----
  const float4* s4 = reinterpret_cast<const float4*>(s + rowbase * kP);
  float4* s_flat = &s_lds[0][0];
#pragma unroll
  for (int i = 0; i < 4; ++i) s_flat[t + 256 * i] = s4[t + 256 * i];

  // ---- stream this block's 64 z rows; per-thread partial over its 8 rows ----
  const float4* z4 = reinterpret_cast<const float4*>(z + rowbase * kC);
  float sx = 0.f, sy = 0.f, sz = 0.f, sw = 0.f, q = 0.f;
#pragma unroll
  for (int j = 0; j < 8; ++j) {
    const float4 v = z4[(tg + 8 * j) * 32 + cq];
    sx += v.x; sy += v.y; sz += v.z; sw += v.w;
    q += v.x * v.x + v.y * v.y + v.z * v.z + v.w * v.w;
  }
  red[tg][cq] = make_float4(sx, sy, sz, sw);
  for (int off = 32; off > 0; off >>= 1) q += __shfl_down(q, off, 64);
  if ((t & 63) == 0) qred[t >> 6] = q;

  __syncthreads();  // covers k/s staging + red/qred

  // ---- finish z reduction: 32 lanes (tg==0) fold 8 row-groups, atomics into ws ----
  if (tg == 0) {
    float4 tot = red[0][cq];
#pragma unroll
    for (int j = 1; j < 8; ++j) {
      const float4 v = red[j][cq];
      tot.x += v.x; tot.y += v.y; tot.z += v.z; tot.w += v.w;
    }
    atomicAdd(&zsum[b * kC + cq * 4 + 0], tot.x);
    atomicAdd(&zsum[b * kC + cq * 4 + 1], tot.y);
    atomicAdd(&zsum[b * kC + cq * 4 + 2], tot.z);
    atomicAdd(&zsum[b * kC + cq * 4 + 3], tot.w);
    if (cq == 0) atomicAdd(&z2[b], qred[0] + qred[1] + qred[2] + qred[3]);
  }

  // ---- GEMM: each thread 8 rows x 1 float4 of c ----
  float4 acc[8];
#pragma unroll
  for (int j = 0; j < 8; ++j) acc[j] = make_float4(0.f, 0.f, 0.f, 0.f);

  for (int pc = 0; pc < 16; ++pc) {  // p in chunks of 4
    const float4 k0 = k_lds[4 * pc + 0][cq];
    const float4 k1 = k_lds[4 * pc + 1][cq];
    const float4 k2 = k_lds[4 * pc + 2][cq];
    const float4 k3 = k_lds[4 * pc + 3][cq];
#pragma unroll
    for (int j = 0; j < 8; ++j) {
      const float4 sv = s_lds[tg + 8 * j][pc];  // LDS broadcast across 32 lanes
      acc[j].x += sv.x * k0.x + sv.y * k1.x + sv.z * k2.x + sv.w * k3.x;
      acc[j].y += sv.x * k0.y + sv.y * k1.y + sv.z * k2.y + sv.w * k3.y;
      acc[j].z += sv.x * k0.z + sv.y * k1.z + sv.z * k2.z + sv.w * k3.z;
      acc[j].w += sv.x * k0.w + sv.y * k1.w + sv.z * k2.w + sv.w * k3.w;
    }
  }

  float4* out4 = reinterpret_cast<float4*>(out + rowbase * kC);
#pragma unroll
  for (int j = 0; j < 8; ++j) out4[(tg + 8 * j) * 32 + cq] = acc[j];
}

// distance[b][p] = z2[b] - 2*dot(zsum[b],k[p]) + 4096*||k[p]||^2
__global__ __launch_bounds__(256) void dist_kernel(const float* __restrict__ zsum,
                                                   const float* __restrict__ z2,
                                                   const float* __restrict__ kmat,
                                                   float* __restrict__ dist) {
  const int g = blockIdx.x * 256 + threadIdx.x;  // 0..4095
  const int b = g >> 6;
  const int p = g & 63;
  float dot = 0.f, k2 = 0.f;
  for (int c = 0; c < kC; ++c) {
    const float kv = kmat[p * kC + c];
    dot += zsum[b * kC + c] * kv;
    k2 += kv * kv;
  }
  dist[g] = z2[b] - 2.f * dot + (float)kHW * k2;
}

}  // namespace

extern "C" void kernel_launch(void* const* d_in, const int* in_sizes, int n_in,
                              void* d_out, int out_size, void* d_ws, size_t ws_size,
                              hipStream_t stream) {
  const float* z = (const float*)d_in[0];      // (64,64,64,128)
  const float* s = (const float*)d_in[1];      // (64,64,64,64)
  const float* kmat = (const float*)d_in[2];   // (64,1,1,128)

  float* out = (float*)d_out;                  // 33554432 floats
  float* dist = out + kOutElems;               // 4096 floats

  float* zsum = (float*)d_ws;                  // 64*128 floats
  float* z2 = zsum + kBB * kC;                 // 64 floats

  // zero the atomic accumulators (ws is poisoned 0xAA each call)
  hipMemsetAsync(d_ws, 0, (size_t)(kBB * kC + kBB) * sizeof(float), stream);

  fused_kernel<<<(int)(kRows / 64), 256, 0, stream>>>(z, s, kmat, out, zsum, z2);
  dist_kernel<<<16, 256, 0, stream>>>(zsum, z2, kmat, dist);
}